// Round 1
// baseline (36.643 us; speedup 1.0000x reference)
//
#include <hip/hip_runtime.h>
#include <hip/hip_bf16.h>

// Problem constants (from reference setup): B=64, S=512, H=1024, fp32.
// Stream compaction per batch row: stable-move rows with valid_ids==1 to the
// front, zero-pad the rest.

// ---------------------------------------------------------------------------
// Kernel 1: per-batch stable prefix-sum over the validity mask.
//   src[b*S + dest] = s   for each valid s (dest = # valid positions before s)
//   nvalid[b]       = total valid count
// One block per batch row, S threads (S=512 -> 8 waves of 64).
// ---------------------------------------------------------------------------
__global__ void build_index_kernel(const int* __restrict__ valid,
                                   int* __restrict__ src,
                                   int* __restrict__ nvalid,
                                   int S) {
    const int b = blockIdx.x;
    const int s = threadIdx.x;            // S threads, one per position
    const int lane = threadIdx.x & 63;
    const int wave = threadIdx.x >> 6;

    const int v = (valid[b * S + s] == 1) ? 1 : 0;

    // 64-lane ballot; prefix within wave via popcount of lower lanes.
    unsigned long long bal = __ballot(v != 0);
    unsigned long long lower = (lane == 0) ? 0ull : (bal & ((1ull << lane) - 1ull));
    int in_wave_prefix = __popcll(lower);
    int wave_total = __popcll(bal);

    __shared__ int wsum[8];
    __shared__ int woff[8];
    if (lane == 0) wsum[wave] = wave_total;
    __syncthreads();
    if (threadIdx.x == 0) {
        int acc = 0;
        #pragma unroll
        for (int w = 0; w < 8; ++w) { woff[w] = acc; acc += wsum[w]; }
        nvalid[b] = acc;
    }
    __syncthreads();

    if (v) {
        src[b * S + woff[wave] + in_wave_prefix] = s;
    }
}

// ---------------------------------------------------------------------------
// Kernel 2: one block per OUTPUT row (b, j). 256 threads x float4 = 1024 fp32.
//   j <  nvalid[b] : copy input row src[b][j]
//   j >= nvalid[b] : write zeros
// Every output element written exactly once; coalesced 16B/lane.
// ---------------------------------------------------------------------------
__global__ void gather_rows_kernel(const float4* __restrict__ in,
                                   float4* __restrict__ out,
                                   const int* __restrict__ src,
                                   const int* __restrict__ nvalid,
                                   int S, int H4) {
    const int bid = blockIdx.x;           // b * S + j
    const int b = bid >> 9;               // S = 512
    const int j = bid & 511;
    const int t = threadIdx.x;            // H4 threads (256)

    const long long orow = (long long)bid * H4;
    if (j < nvalid[b]) {
        const int s = src[b * S + j];
        const long long irow = ((long long)b * S + s) * (long long)H4;
        out[orow + t] = in[irow + t];
    } else {
        out[orow + t] = make_float4(0.f, 0.f, 0.f, 0.f);
    }
}

extern "C" void kernel_launch(void* const* d_in, const int* in_sizes, int n_in,
                              void* d_out, int out_size, void* d_ws, size_t ws_size,
                              hipStream_t stream) {
    const float* seq = (const float*)d_in[0];   // [B, S, H] fp32
    const int* valid = (const int*)d_in[1];     // [B, S] int32

    const int S = 512;
    const int BS = in_sizes[1];                 // B * S
    const int B = BS / S;
    const int H = in_sizes[0] / BS;             // 1024
    const int H4 = H / 4;                       // 256

    // Workspace layout: src[B*S] ints, then nvalid[B] ints.
    int* src = (int*)d_ws;
    int* nvalid = src + BS;

    build_index_kernel<<<B, S, 0, stream>>>(valid, src, nvalid, S);

    gather_rows_kernel<<<BS, H4, 0, stream>>>(
        (const float4*)seq, (float4*)d_out, src, nvalid, S, H4);
}